// Round 6
// baseline (188.691 us; speedup 1.0000x reference)
//
#include <hip/hip_runtime.h>
#include <hip/hip_bf16.h>

#define BATCH 4
#define HH 128
#define WW 128
#define CE 32
#define CF 64
#define CIN 96
#define KK 9
#define COUT 64

typedef __bf16 bf16x8 __attribute__((ext_vector_type(8)));
typedef float f32x4 __attribute__((ext_vector_type(4)));
#define MFMA16(a, b, c) __builtin_amdgcn_mfma_f32_16x16x32_bf16(a, b, c, 0, 0, 0)
typedef union { uint4 u; bf16x8 v; } U8;

// ---- workspace byte offsets ----
#define OX_BYTES   (BATCH * HH * WW * CIN * 2)      // 12,582,912  bf16 NHWC
#define WCT_OFFB   OX_BYTES
#define WCT_BYTES  (32 * 864 * 2)
#define WKT_OFFB   (WCT_OFFB + WCT_BYTES)

// Fused LN(evt)+LN(efnet)+concat -> ox bf16 NHWC, 64 px/block, 256 thr.
// Also repacks conv weights (grid-strided over first 325 blocks' threads):
//   wcombT[oc32][864] bf16 (oc<18 offset, 18..26 mask, 27..31 zero)
//   wkT[oc64][864] bf16,  k = tap*96 + c
__global__ __launch_bounds__(256) void ln_concat_prep(
    const float* __restrict__ evt, const float* __restrict__ efn,
    const float* __restrict__ w_e, const float* __restrict__ b_e,
    const float* __restrict__ w_f, const float* __restrict__ b_f,
    const float* __restrict__ off_w, const float* __restrict__ mod_w,
    const float* __restrict__ reg_w,
    __hip_bfloat16* __restrict__ ox,
    __hip_bfloat16* __restrict__ wcombT,
    __hip_bfloat16* __restrict__ wkT) {
  __shared__ float vals[64 * 97];
  __shared__ float part[4 * 64 * 4];
  __shared__ float stat[64 * 4];

  // ---- weight repack (independent of LN work) ----
  {
    int e = blockIdx.x * 256 + threadIdx.x;
    const int TOT1 = 32 * 864, TOT2 = 64 * 864;
    if (e < TOT1) {
      int oc = e / 864, k = e % 864;
      int tap = k / 96, c = k % 96;
      float v = 0.f;
      if (oc < 18)      v = off_w[(oc * CIN + c) * KK + tap];
      else if (oc < 27) v = mod_w[((oc - 18) * CIN + c) * KK + tap];
      wcombT[e] = __float2bfloat16(v);
    } else if (e < TOT1 + TOT2) {
      int e2 = e - TOT1;
      int oc = e2 / 864, k = e2 % 864;
      int tap = k / 96, c = k % 96;
      wkT[e2] = __float2bfloat16(reg_w[(oc * CIN + c) * KK + tap]);
    }
  }

  int bid = blockIdx.x;
  int wg = (bid & 7) * 128 + (bid >> 3);     // XCD-chunked swizzle
  int p0 = wg * 64;
  int b = p0 >> 14, y = (p0 >> 7) & 127, x0 = p0 & 127;
  int t = threadIdx.x, px = t & 63, g = t >> 6;

  float sE = 0.f, sE2 = 0.f, sF = 0.f, sF2 = 0.f;
  const float* pe = evt + (((size_t)b * CE) << 14) + (y << 7) + x0 + px;
#pragma unroll
  for (int j = 0; j < 8; ++j) {
    int c = g * 8 + j;
    float v = pe[(size_t)c << 14];
    vals[px * 97 + c] = v; sE += v; sE2 += v * v;
  }
  const float* pf = efn + (((size_t)b * CF) << 14) + (y << 7) + x0 + px;
#pragma unroll
  for (int j = 0; j < 16; ++j) {
    int c = g * 16 + j;
    float v = pf[(size_t)c << 14];
    vals[px * 97 + CE + c] = v; sF += v; sF2 += v * v;
  }
  {
    float4 p4 = {sE, sE2, sF, sF2};
    *(float4*)&part[(g * 64 + px) * 4] = p4;
  }
  __syncthreads();
  if (g == 0) {
    float aE = 0.f, aE2 = 0.f, aF = 0.f, aF2 = 0.f;
#pragma unroll
    for (int gg = 0; gg < 4; ++gg) {
      float4 p4 = *(const float4*)&part[(gg * 64 + px) * 4];
      aE += p4.x; aE2 += p4.y; aF += p4.z; aF2 += p4.w;
    }
    float muE = aE * (1.f / CE);
    float vE = aE2 * (1.f / CE) - muE * muE;
    float muF = aF * (1.f / CF);
    float vF = aF2 * (1.f / CF) - muF * muF;
    float4 s4 = {muE, rsqrtf(vE + 1e-5f), muF, rsqrtf(vF + 1e-5f)};
    *(float4*)&stat[px * 4] = s4;
  }
  __syncthreads();
  uint* orow = (uint*)(ox + (size_t)p0 * CIN);
#pragma unroll
  for (int i = 0; i < 12; ++i) {
    int e = i * 256 + t;
    int xx = e / 48, c = (e % 48) * 2;
    float v0 = vals[xx * 97 + c], v1 = vals[xx * 97 + c + 1];
    float mu, rs, lw0, lb0, lw1, lb1;
    if (c < CE) {
      mu = stat[xx * 4 + 0]; rs = stat[xx * 4 + 1];
      lw0 = w_e[c]; lb0 = b_e[c]; lw1 = w_e[c + 1]; lb1 = b_e[c + 1];
    } else {
      mu = stat[xx * 4 + 2]; rs = stat[xx * 4 + 3];
      lw0 = w_f[c - CE]; lb0 = b_f[c - CE]; lw1 = w_f[c + 1 - CE]; lb1 = b_f[c + 1 - CE];
    }
    float o0 = (v0 - mu) * rs * lw0 + lb0;
    float o1 = (v1 - mu) * rs * lw1 + lb1;
    __hip_bfloat16 h0 = __float2bfloat16(o0), h1 = __float2bfloat16(o1);
    orow[e] = ((uint)*(unsigned short*)&h1 << 16) | (uint)*(unsigned short*)&h0;
  }
}

__device__ __forceinline__ uint blend1(uint u0, uint u1, uint u2, uint u3,
                                       float w0, float w1, float w2, float w3) {
  float lo = w0 * __uint_as_float(u0 << 16) + w1 * __uint_as_float(u1 << 16)
           + w2 * __uint_as_float(u2 << 16) + w3 * __uint_as_float(u3 << 16);
  float hi = w0 * __uint_as_float(u0 & 0xffff0000u) + w1 * __uint_as_float(u1 & 0xffff0000u)
           + w2 * __uint_as_float(u2 & 0xffff0000u) + w3 * __uint_as_float(u3 & 0xffff0000u);
  __hip_bfloat16 bl = __float2bfloat16(lo), bh = __float2bfloat16(hi);
  return ((uint)*(unsigned short*)&bh << 16) | (uint)*(unsigned short*)&bl;
}

// Fused conv(27ch)->deform->bias/leaky/LN, BARRIER-FREE.
// Each wave owns a 16-px x 64-oc output tile (M=16 = MFMA M). A-fragments
// (conv: shifted window; deform: bilinear blend) are built per-lane directly
// in registers from global loads — lane (lr,lg) holds row=lr=its px,
// k=lg*8(+ks*32). offm and outl LDS are wave-local (no __syncthreads).
__global__ __launch_bounds__(256, 4) void conv_deform_fused(
    const __hip_bfloat16* __restrict__ ox,
    const __hip_bfloat16* __restrict__ wcombT,
    const __hip_bfloat16* __restrict__ wkT,
    const float* __restrict__ off_b, const float* __restrict__ mod_b,
    const float* __restrict__ reg_b,
    const float* __restrict__ lnw, const float* __restrict__ lnb,
    float* __restrict__ out) {
  __shared__ float offm[64 * 28];     // [px][27] offsets+mask  (wave-local)
  __shared__ float outl[64 * 65];     // [px][64] epilogue      (wave-local)

  int bid = blockIdx.x;
  int wg = (bid & 7) * 128 + (bid >> 3);   // XCD-chunked swizzle
  int p0 = wg * 64;
  int b = p0 >> 14, y = (p0 >> 7) & 127, x0 = p0 & 127;
  const __hip_bfloat16* oxb = ox + (((size_t)b) << 14) * CIN;

  int t = threadIdx.x, lane = t & 63, wv = t >> 6;
  int lr = lane & 15, lg = lane >> 4;
  int pxw = (wv << 4) + lr;                // this lane's A-row pixel

  // ---- conv phase: offset/mask conv, fragments straight from global ----
  f32x4 cc0 = {0.f,0.f,0.f,0.f}, cc1 = {0.f,0.f,0.f,0.f};
  {
    const __hip_bfloat16* br0 = wcombT + (size_t)lr * 864 + lg * 8;
    const __hip_bfloat16* br1 = wcombT + (size_t)(16 + lr) * 864 + lg * 8;
    for (int tap = 0; tap < 9; ++tap) {
      int yy = y + tap / 3 - 1;
      int xx = x0 + pxw + tap % 3 - 1;
      bool valid = ((unsigned)yy < 128u) && ((unsigned)xx < 128u);
      int cy = min(max(yy, 0), 127), cx = min(max(xx, 0), 127);
      const __hip_bfloat16* arow = oxb + (size_t)((cy << 7) + cx) * CIN + lg * 8;
#pragma unroll
      for (int ks = 0; ks < 3; ++ks) {
        U8 a, w0, w1;
        a.u = *(const uint4*)(arow + ks * 32);
        if (!valid) { a.u.x = 0; a.u.y = 0; a.u.z = 0; a.u.w = 0; }
        w0.u = *(const uint4*)(br0 + tap * 96 + ks * 32);
        w1.u = *(const uint4*)(br1 + tap * 96 + ks * 32);
        cc0 = MFMA16(a.v, w0.v, cc0);
        cc1 = MFMA16(a.v, w1.v, cc1);
      }
    }
  }
  // offm epilogue — wave-local (wave wv wrote and reads px range wv*16..+15)
#pragma unroll
  for (int nt = 0; nt < 2; ++nt) {
    int oc = nt * 16 + lr;
    if (oc < 27) {
      float bia = (oc < 18) ? off_b[oc] : mod_b[oc - 18];
      f32x4 a = nt ? cc1 : cc0;
#pragma unroll
      for (int r = 0; r < 4; ++r) {
        int pxc = (wv << 4) + (lg << 2) + r;
        float v = a[r] + bia;
        if (oc >= 18) v = 2.f / (1.f + __expf(-v));
        offm[pxc * 28 + oc] = v;
      }
    }
  }

  // ---- deform phase: per-lane register fragments, tap+1 prefetched ----
  const float* om = offm + pxw * 28;
  const __hip_bfloat16* gb = oxb + lg * 8;
  f32x4 ac0 = {0.f,0.f,0.f,0.f}, ac1 = {0.f,0.f,0.f,0.f};
  f32x4 ac2 = {0.f,0.f,0.f,0.f}, ac3 = {0.f,0.f,0.f,0.f};

  uint4 qa0,qa1,qa2,qa3, qb0,qb1,qb2,qb3, qc0,qc1,qc2,qc3;
  float pw0, pw1, pw2, pw3;

#define ISSUE(T)                                                             \
  {                                                                          \
    float dyv = om[2 * (T)], dxv = om[2 * (T) + 1], mk = om[18 + (T)];       \
    float psy = (float)(y + (T) / 3 - 1) + dyv;                              \
    float psx = (float)(x0 + pxw + (T) % 3 - 1) + dxv;                       \
    float fy = floorf(psy), fx = floorf(psx);                                \
    float wy1 = psy - fy, wx1 = psx - fx;                                    \
    float wy0 = 1.f - wy1, wx0 = 1.f - wx1;                                  \
    int iy0 = (int)fy, ix0 = (int)fx, iy1 = iy0 + 1, ix1 = ix0 + 1;          \
    float vy0 = ((unsigned)iy0 < 128u) ? 1.f : 0.f;                          \
    float vy1 = ((unsigned)iy1 < 128u) ? 1.f : 0.f;                          \
    float vx0 = ((unsigned)ix0 < 128u) ? 1.f : 0.f;                          \
    float vx1 = ((unsigned)ix1 < 128u) ? 1.f : 0.f;                          \
    int cy0 = min(max(iy0, 0), 127), cy1 = min(max(iy1, 0), 127);            \
    int cx0 = min(max(ix0, 0), 127), cx1 = min(max(ix1, 0), 127);            \
    int i00 = ((cy0 << 7) + cx0) * CIN, i01 = ((cy0 << 7) + cx1) * CIN;      \
    int i10 = ((cy1 << 7) + cx0) * CIN, i11 = ((cy1 << 7) + cx1) * CIN;      \
    pw0 = wy0 * wx0 * vy0 * vx0 * mk; pw1 = wy0 * wx1 * vy0 * vx1 * mk;      \
    pw2 = wy1 * wx0 * vy1 * vx0 * mk; pw3 = wy1 * wx1 * vy1 * vx1 * mk;      \
    qa0 = *(const uint4*)(gb + i00);      qa1 = *(const uint4*)(gb + i01);   \
    qa2 = *(const uint4*)(gb + i10);      qa3 = *(const uint4*)(gb + i11);   \
    qb0 = *(const uint4*)(gb + i00 + 32); qb1 = *(const uint4*)(gb + i01 + 32);\
    qb2 = *(const uint4*)(gb + i10 + 32); qb3 = *(const uint4*)(gb + i11 + 32);\
    qc0 = *(const uint4*)(gb + i00 + 64); qc1 = *(const uint4*)(gb + i01 + 64);\
    qc2 = *(const uint4*)(gb + i10 + 64); qc3 = *(const uint4*)(gb + i11 + 64);\
  }

  ISSUE(0);
  for (int tap = 0; tap < 9; ++tap) {
    U8 fa0, fa1, fa2;
    fa0.u.x = blend1(qa0.x, qa1.x, qa2.x, qa3.x, pw0, pw1, pw2, pw3);
    fa0.u.y = blend1(qa0.y, qa1.y, qa2.y, qa3.y, pw0, pw1, pw2, pw3);
    fa0.u.z = blend1(qa0.z, qa1.z, qa2.z, qa3.z, pw0, pw1, pw2, pw3);
    fa0.u.w = blend1(qa0.w, qa1.w, qa2.w, qa3.w, pw0, pw1, pw2, pw3);
    fa1.u.x = blend1(qb0.x, qb1.x, qb2.x, qb3.x, pw0, pw1, pw2, pw3);
    fa1.u.y = blend1(qb0.y, qb1.y, qb2.y, qb3.y, pw0, pw1, pw2, pw3);
    fa1.u.z = blend1(qb0.z, qb1.z, qb2.z, qb3.z, pw0, pw1, pw2, pw3);
    fa1.u.w = blend1(qb0.w, qb1.w, qb2.w, qb3.w, pw0, pw1, pw2, pw3);
    fa2.u.x = blend1(qc0.x, qc1.x, qc2.x, qc3.x, pw0, pw1, pw2, pw3);
    fa2.u.y = blend1(qc0.y, qc1.y, qc2.y, qc3.y, pw0, pw1, pw2, pw3);
    fa2.u.z = blend1(qc0.z, qc1.z, qc2.z, qc3.z, pw0, pw1, pw2, pw3);
    fa2.u.w = blend1(qc0.w, qc1.w, qc2.w, qc3.w, pw0, pw1, pw2, pw3);
    if (tap < 8) {
      int tn = tap + 1;
      ISSUE(tn);
    }
    const __hip_bfloat16* wr = wkT + (size_t)lr * 864 + tap * 96 + lg * 8;
    U8 b0, b1, b2;
#define MSTEP(ACC, ROWOFF)                                                   \
    b0.u = *(const uint4*)(wr + (ROWOFF) * 864);                             \
    b1.u = *(const uint4*)(wr + (ROWOFF) * 864 + 32);                        \
    b2.u = *(const uint4*)(wr + (ROWOFF) * 864 + 64);                        \
    ACC = MFMA16(fa0.v, b0.v, ACC);                                          \
    ACC = MFMA16(fa1.v, b1.v, ACC);                                          \
    ACC = MFMA16(fa2.v, b2.v, ACC);
    MSTEP(ac0, 0)
    MSTEP(ac1, 16)
    MSTEP(ac2, 32)
    MSTEP(ac3, 48)
#undef MSTEP
  }
#undef ISSUE

  // ---- epilogue: bias+leaky -> outl (wave-local), LN, store ----
#pragma unroll
  for (int nt = 0; nt < 4; ++nt) {
    int oc = nt * 16 + lr;
    float bia = reg_b[oc];
    f32x4 a = (nt == 0) ? ac0 : (nt == 1) ? ac1 : (nt == 2) ? ac2 : ac3;
#pragma unroll
    for (int r = 0; r < 4; ++r) {
      int pxc = (wv << 4) + (lg << 2) + r;
      float v = a[r] + bia;
      v = (v >= 0.f) ? v : 0.2f * v;
      outl[pxc * 65 + oc] = v;
    }
  }
  {
    int px2 = (wv << 4) + (lane >> 2);   // within this wave's px range
    int part = lane & 3;
    float s = 0.f, s2 = 0.f;
#pragma unroll
    for (int j = 0; j < 16; ++j) {
      float v = outl[px2 * 65 + part * 16 + j];
      s += v; s2 += v * v;
    }
    s += __shfl_xor(s, 1); s2 += __shfl_xor(s2, 1);
    s += __shfl_xor(s, 2); s2 += __shfl_xor(s2, 2);
    float mu = s * (1.f / 64.f);
    float var = s2 * (1.f / 64.f) - mu * mu;
    float rs = rsqrtf(var + 1e-5f);
    size_t ob = (size_t)b * COUT * 16384 + (size_t)y * 128 + x0 + px2;
#pragma unroll
    for (int j = 0; j < 16; ++j) {
      int oc = part * 16 + j;
      float v = outl[px2 * 65 + oc];
      out[ob + (size_t)oc * 16384] = (v - mu) * rs * lnw[oc] + lnb[oc];
    }
  }
}

extern "C" void kernel_launch(void* const* d_in, const int* in_sizes, int n_in,
                              void* d_out, int out_size, void* d_ws, size_t ws_size,
                              hipStream_t stream) {
  const float* evt      = (const float*)d_in[0];
  const float* efn      = (const float*)d_in[1];
  const float* ln_evt_w = (const float*)d_in[2];
  const float* ln_evt_b = (const float*)d_in[3];
  const float* ln_ef_w  = (const float*)d_in[4];
  const float* ln_ef_b  = (const float*)d_in[5];
  const float* ln_al_w  = (const float*)d_in[6];
  const float* ln_al_b  = (const float*)d_in[7];
  const float* off_w    = (const float*)d_in[8];
  const float* off_b    = (const float*)d_in[9];
  const float* mod_w    = (const float*)d_in[10];
  const float* mod_b    = (const float*)d_in[11];
  const float* reg_w    = (const float*)d_in[12];
  const float* reg_b    = (const float*)d_in[13];
  float* out = (float*)d_out;

  char* wsb = (char*)d_ws;
  __hip_bfloat16* oxb    = (__hip_bfloat16*)wsb;
  __hip_bfloat16* wcombT = (__hip_bfloat16*)(wsb + WCT_OFFB);
  __hip_bfloat16* wkT    = (__hip_bfloat16*)(wsb + WKT_OFFB);

  ln_concat_prep<<<BATCH * HH * WW / 64, 256, 0, stream>>>(
      evt, efn, ln_evt_w, ln_evt_b, ln_ef_w, ln_ef_b,
      off_w, mod_w, reg_w, oxb, wcombT, wkT);
  conv_deform_fused<<<BATCH * HH * WW / 64, 256, 0, stream>>>(
      oxb, wcombT, wkT, off_b, mod_b, reg_b, ln_al_w, ln_al_b, out);
}

// Round 7
// 186.275 us; speedup vs baseline: 1.0130x; 1.0130x over previous
//
#include <hip/hip_runtime.h>
#include <hip/hip_bf16.h>

#define BATCH 4
#define HH 128
#define WW 128
#define CE 32
#define CF 64
#define CIN 96
#define COUT 64

typedef __bf16 bf16x8 __attribute__((ext_vector_type(8)));
typedef float f32x4 __attribute__((ext_vector_type(4)));
#define MFMA16(a, b, c) __builtin_amdgcn_mfma_f32_16x16x32_bf16(a, b, c, 0, 0, 0)
typedef union { uint4 u; bf16x8 v; } U8;

// ---- workspace byte offsets ----
#define OX_BYTES   (BATCH * HH * WW * CIN * 2)      // 12,582,912  bf16 NHWC
#define WCT_OFFB   OX_BYTES
#define WCT_BYTES  (27 * 32 * 32 * 2)               // 55,296 B
#define WKT_OFFB   (WCT_OFFB + WCT_BYTES)           // wkT2: 27*64*32 bf16 = 110,592 B

// Weight layouts (fragment-coalesced):
//   wcombT2[(tap*3+ks)*32 + oc][r]  r = lg*8+j -> channel c = ks*32 + r
//   wkT2  [(tap*3+ks)*64 + oc][r]
// One B-fragment load instr = 64 lanes x 16B contiguous (1KB run).

// Fused LN(evt)+LN(efnet)+concat -> ox bf16 NHWC, 64 px/block, 256 thr.
// Also repacks conv/deform weights to the fragment-coalesced layout.
__global__ __launch_bounds__(256) void ln_concat_prep(
    const float* __restrict__ evt, const float* __restrict__ efn,
    const float* __restrict__ w_e, const float* __restrict__ b_e,
    const float* __restrict__ w_f, const float* __restrict__ b_f,
    const float* __restrict__ off_w, const float* __restrict__ mod_w,
    const float* __restrict__ reg_w,
    __hip_bfloat16* __restrict__ ox,
    __hip_bfloat16* __restrict__ wcombT2,
    __hip_bfloat16* __restrict__ wkT2) {
  __shared__ float vals[64 * 97];
  __shared__ float part[4 * 64 * 4];
  __shared__ float stat[64 * 4];

  // ---- weight repack ----
  {
    int e = blockIdx.x * 256 + threadIdx.x;
    const int TOT1 = 27 * 32 * 32;   // 27648
    const int TOT2 = 27 * 64 * 32;   // 55296
    if (e < TOT1) {
      int r = e & 31, g = e >> 5;
      int oc = g & 31, tks = g >> 5;
      int tap = tks / 3, ks = tks % 3, c = ks * 32 + r;
      float v = 0.f;
      if (oc < 18)      v = off_w[(oc * CIN + c) * 9 + tap];
      else if (oc < 27) v = mod_w[((oc - 18) * CIN + c) * 9 + tap];
      wcombT2[e] = __float2bfloat16(v);
    } else if (e < TOT1 + TOT2) {
      int e2 = e - TOT1;
      int r = e2 & 31, g = e2 >> 5;
      int oc = g & 63, tks = g >> 6;
      int tap = tks / 3, ks = tks % 3, c = ks * 32 + r;
      wkT2[e2] = __float2bfloat16(reg_w[(oc * CIN + c) * 9 + tap]);
    }
  }

  int bid = blockIdx.x;
  int wg = (bid & 7) * 128 + (bid >> 3);     // XCD-chunked swizzle (1024 = 8*128)
  int p0 = wg * 64;
  int b = p0 >> 14, y = (p0 >> 7) & 127, x0 = p0 & 127;
  int t = threadIdx.x, px = t & 63, g = t >> 6;

  float sE = 0.f, sE2 = 0.f, sF = 0.f, sF2 = 0.f;
  const float* pe = evt + (((size_t)b * CE) << 14) + (y << 7) + x0 + px;
#pragma unroll
  for (int j = 0; j < 8; ++j) {
    int c = g * 8 + j;
    float v = pe[(size_t)c << 14];
    vals[px * 97 + c] = v; sE += v; sE2 += v * v;
  }
  const float* pf = efn + (((size_t)b * CF) << 14) + (y << 7) + x0 + px;
#pragma unroll
  for (int j = 0; j < 16; ++j) {
    int c = g * 16 + j;
    float v = pf[(size_t)c << 14];
    vals[px * 97 + CE + c] = v; sF += v; sF2 += v * v;
  }
  {
    float4 p4 = {sE, sE2, sF, sF2};
    *(float4*)&part[(g * 64 + px) * 4] = p4;
  }
  __syncthreads();
  if (g == 0) {
    float aE = 0.f, aE2 = 0.f, aF = 0.f, aF2 = 0.f;
#pragma unroll
    for (int gg = 0; gg < 4; ++gg) {
      float4 p4 = *(const float4*)&part[(gg * 64 + px) * 4];
      aE += p4.x; aE2 += p4.y; aF += p4.z; aF2 += p4.w;
    }
    float muE = aE * (1.f / CE);
    float vE = aE2 * (1.f / CE) - muE * muE;
    float muF = aF * (1.f / CF);
    float vF = aF2 * (1.f / CF) - muF * muF;
    float4 s4 = {muE, rsqrtf(vE + 1e-5f), muF, rsqrtf(vF + 1e-5f)};
    *(float4*)&stat[px * 4] = s4;
  }
  __syncthreads();
  uint* orow = (uint*)(ox + (size_t)p0 * CIN);
#pragma unroll
  for (int i = 0; i < 12; ++i) {
    int e = i * 256 + t;
    int xx = e / 48, c = (e % 48) * 2;
    float v0 = vals[xx * 97 + c], v1 = vals[xx * 97 + c + 1];
    float mu, rs, lw0, lb0, lw1, lb1;
    if (c < CE) {
      mu = stat[xx * 4 + 0]; rs = stat[xx * 4 + 1];
      lw0 = w_e[c]; lb0 = b_e[c]; lw1 = w_e[c + 1]; lb1 = b_e[c + 1];
    } else {
      mu = stat[xx * 4 + 2]; rs = stat[xx * 4 + 3];
      lw0 = w_f[c - CE]; lb0 = b_f[c - CE]; lw1 = w_f[c + 1 - CE]; lb1 = b_f[c + 1 - CE];
    }
    float o0 = (v0 - mu) * rs * lw0 + lb0;
    float o1 = (v1 - mu) * rs * lw1 + lb1;
    __hip_bfloat16 h0 = __float2bfloat16(o0), h1 = __float2bfloat16(o1);
    orow[e] = ((uint)*(unsigned short*)&h1 << 16) | (uint)*(unsigned short*)&h0;
  }
}

__device__ __forceinline__ uint blend1(uint u0, uint u1, uint u2, uint u3,
                                       float w0, float w1, float w2, float w3) {
  float lo = w0 * __uint_as_float(u0 << 16) + w1 * __uint_as_float(u1 << 16)
           + w2 * __uint_as_float(u2 << 16) + w3 * __uint_as_float(u3 << 16);
  float hi = w0 * __uint_as_float(u0 & 0xffff0000u) + w1 * __uint_as_float(u1 & 0xffff0000u)
           + w2 * __uint_as_float(u2 & 0xffff0000u) + w3 * __uint_as_float(u3 & 0xffff0000u);
  __hip_bfloat16 bl = __float2bfloat16(lo), bh = __float2bfloat16(hi);
  return ((uint)*(unsigned short*)&bh << 16) | (uint)*(unsigned short*)&bl;
}

// Fused conv(27ch)->deform->bias/leaky/LN. ONE WAVE per block, 16 px.
// Grid 4096 -> 16 blocks/CU potential; ~6KB LDS; zero inter-wave sync.
// 27-chunk (tap,ks) pipeline: B-load -> blend(cc) -> prefetch gathers(cc+1)
// -> 4 MFMA. Compiler's counted FIFO vmcnt keeps the prefetch in flight.
__global__ __launch_bounds__(64) void conv_deform_fused(
    const __hip_bfloat16* __restrict__ ox,
    const __hip_bfloat16* __restrict__ wct2,
    const __hip_bfloat16* __restrict__ wkt2,
    const float* __restrict__ off_b, const float* __restrict__ mod_b,
    const float* __restrict__ reg_b,
    const float* __restrict__ lnw, const float* __restrict__ lnb,
    float* __restrict__ out) {
  __shared__ float offm[16 * 28];     // [px][27]  1792 B
  __shared__ float outl[16 * 65];     // [px][64]  4160 B

  int bid = blockIdx.x;
  int wg = (bid & 7) * 512 + (bid >> 3);   // XCD-chunked swizzle (4096 = 8*512)
  int p0 = wg * 16;
  int b = p0 >> 14, y = (p0 >> 7) & 127, x0 = p0 & 127;
  const __hip_bfloat16* oxb = ox + (((size_t)b) << 14) * CIN;

  int lane = threadIdx.x, lr = lane & 15, lg = lane >> 4;

  // ---- conv phase: A per-lane from global, B coalesced 1KB fragments ----
  f32x4 cc0 = {0.f,0.f,0.f,0.f}, cc1 = {0.f,0.f,0.f,0.f};
#pragma unroll
  for (int tap = 0; tap < 9; ++tap) {
    int yy = y + tap / 3 - 1;
    int xx = x0 + lr + tap % 3 - 1;
    bool valid = ((unsigned)yy < 128u) && ((unsigned)xx < 128u);
    int cy = min(max(yy, 0), 127), cx = min(max(xx, 0), 127);
    const __hip_bfloat16* arow = oxb + (size_t)((cy << 7) + cx) * CIN + lg * 8;
#pragma unroll
    for (int ks = 0; ks < 3; ++ks) {
      U8 a, w0, w1;
      a.u = *(const uint4*)(arow + ks * 32);
      if (!valid) { a.u.x = 0; a.u.y = 0; a.u.z = 0; a.u.w = 0; }
      const __hip_bfloat16* wb = wct2 + (size_t)((tap * 3 + ks) * 32) * 32 + lg * 8;
      w0.u = *(const uint4*)(wb + lr * 32);
      w1.u = *(const uint4*)(wb + (16 + lr) * 32);
      cc0 = MFMA16(a.v, w0.v, cc0);
      cc1 = MFMA16(a.v, w1.v, cc1);
    }
  }
#pragma unroll
  for (int nt = 0; nt < 2; ++nt) {
    int oc = nt * 16 + lr;
    if (oc < 27) {
      float bia = (oc < 18) ? off_b[oc] : mod_b[oc - 18];
      f32x4 a = nt ? cc1 : cc0;
#pragma unroll
      for (int r = 0; r < 4; ++r) {
        float v = a[r] + bia;
        if (oc >= 18) v = 2.f / (1.f + __expf(-v));
        offm[(lg * 4 + r) * 28 + oc] = v;
      }
    }
  }
  __syncthreads();   // single-wave block: trivial; orders LDS write->read

  // ---- deform phase: 27-chunk register pipeline ----
  const float* om = offm + lr * 28;        // lane's px = lr
  f32x4 ac0 = {0.f,0.f,0.f,0.f}, ac1 = {0.f,0.f,0.f,0.f};
  f32x4 ac2 = {0.f,0.f,0.f,0.f}, ac3 = {0.f,0.f,0.f,0.f};

  uint4 q[2][4];        // gather dbuf (chunk parity)
  int   idx[2][4];      // corner indices dbuf (tap parity)
  float pwv[2][4];      // corner weights dbuf (tap parity)

#define PARAMS(T, S)                                                          \
  {                                                                           \
    float dyv = om[2 * (T)], dxv = om[2 * (T) + 1], mk = om[18 + (T)];        \
    float psy = (float)(y + (T) / 3 - 1) + dyv;                               \
    float psx = (float)(x0 + lr + (T) % 3 - 1) + dxv;                         \
    float fy = floorf(psy), fx = floorf(psx);                                 \
    float wy1 = psy - fy, wx1 = psx - fx;                                     \
    float wy0 = 1.f - wy1, wx0 = 1.f - wx1;                                   \
    int iy0 = (int)fy, ix0 = (int)fx, iy1 = iy0 + 1, ix1 = ix0 + 1;           \
    float vy0 = ((unsigned)iy0 < 128u) ? 1.f : 0.f;                           \
    float vy1 = ((unsigned)iy1 < 128u) ? 1.f : 0.f;                           \
    float vx0 = ((unsigned)ix0 < 128u) ? 1.f : 0.f;                           \
    float vx1 = ((unsigned)ix1 < 128u) ? 1.f : 0.f;                           \
    int cy0 = min(max(iy0, 0), 127), cy1 = min(max(iy1, 0), 127);             \
    int cx0 = min(max(ix0, 0), 127), cx1 = min(max(ix1, 0), 127);             \
    idx[S][0] = ((cy0 << 7) + cx0) * CIN;                                     \
    idx[S][1] = ((cy0 << 7) + cx1) * CIN;                                     \
    idx[S][2] = ((cy1 << 7) + cx0) * CIN;                                     \
    idx[S][3] = ((cy1 << 7) + cx1) * CIN;                                     \
    pwv[S][0] = wy0 * wx0 * vy0 * vx0 * mk;                                   \
    pwv[S][1] = wy0 * wx1 * vy0 * vx1 * mk;                                   \
    pwv[S][2] = wy1 * wx0 * vy1 * vx0 * mk;                                   \
    pwv[S][3] = wy1 * wx1 * vy1 * vx1 * mk;                                   \
  }

#define GATHER(QS, PS, KOFF)                                                  \
  {                                                                           \
    q[QS][0] = *(const uint4*)(oxb + idx[PS][0] + (KOFF));                    \
    q[QS][1] = *(const uint4*)(oxb + idx[PS][1] + (KOFF));                    \
    q[QS][2] = *(const uint4*)(oxb + idx[PS][2] + (KOFF));                    \
    q[QS][3] = *(const uint4*)(oxb + idx[PS][3] + (KOFF));                    \
  }

  PARAMS(0, 0);
  GATHER(0, 0, lg * 8);

#pragma unroll
  for (int cc = 0; cc < 27; ++cc) {
    const int tap = cc / 3, ks = cc % 3;
    const int cur = cc & 1, tp = tap & 1;
    // B fragments: contiguous 1KB per instr
    const __hip_bfloat16* wb = wkt2 + (size_t)((tap * 3 + ks) * 64) * 32 + lg * 8;
    U8 b0, b1, b2, b3;
    b0.u = *(const uint4*)(wb + lr * 32);
    b1.u = *(const uint4*)(wb + (16 + lr) * 32);
    b2.u = *(const uint4*)(wb + (32 + lr) * 32);
    b3.u = *(const uint4*)(wb + (48 + lr) * 32);
    // blend current chunk
    U8 fa;
    fa.u.x = blend1(q[cur][0].x, q[cur][1].x, q[cur][2].x, q[cur][3].x,
                    pwv[tp][0], pwv[tp][1], pwv[tp][2], pwv[tp][3]);
    fa.u.y = blend1(q[cur][0].y, q[cur][1].y, q[cur][2].y, q[cur][3].y,
                    pwv[tp][0], pwv[tp][1], pwv[tp][2], pwv[tp][3]);
    fa.u.z = blend1(q[cur][0].z, q[cur][1].z, q[cur][2].z, q[cur][3].z,
                    pwv[tp][0], pwv[tp][1], pwv[tp][2], pwv[tp][3]);
    fa.u.w = blend1(q[cur][0].w, q[cur][1].w, q[cur][2].w, q[cur][3].w,
                    pwv[tp][0], pwv[tp][1], pwv[tp][2], pwv[tp][3]);
    // prefetch next chunk's gathers (params first at tap boundary)
    if (cc < 26) {
      const int nc = cc + 1, ntap = nc / 3, nks = nc % 3;
      const int nxt = nc & 1, ntp = ntap & 1;
      if (nks == 0) PARAMS(ntap, ntp);
      GATHER(nxt, ntp, nks * 32 + lg * 8);
    }
    ac0 = MFMA16(fa.v, b0.v, ac0);
    ac1 = MFMA16(fa.v, b1.v, ac1);
    ac2 = MFMA16(fa.v, b2.v, ac2);
    ac3 = MFMA16(fa.v, b3.v, ac3);
  }
#undef PARAMS
#undef GATHER

  // ---- epilogue: bias+leaky -> outl, channel-LN, store ----
#pragma unroll
  for (int nt = 0; nt < 4; ++nt) {
    int oc = nt * 16 + lr;
    float bia = reg_b[oc];
    f32x4 a = (nt == 0) ? ac0 : (nt == 1) ? ac1 : (nt == 2) ? ac2 : ac3;
#pragma unroll
    for (int r = 0; r < 4; ++r) {
      float v = a[r] + bia;
      v = (v >= 0.f) ? v : 0.2f * v;
      outl[(lg * 4 + r) * 65 + oc] = v;
    }
  }
  __syncthreads();
  {
    int px2 = lane >> 2, part = lane & 3;
    float s = 0.f, s2 = 0.f;
#pragma unroll
    for (int j = 0; j < 16; ++j) {
      float v = outl[px2 * 65 + part * 16 + j];
      s += v; s2 += v * v;
    }
    s += __shfl_xor(s, 1); s2 += __shfl_xor(s2, 1);
    s += __shfl_xor(s, 2); s2 += __shfl_xor(s2, 2);
    float mu = s * (1.f / 64.f);
    float var = s2 * (1.f / 64.f) - mu * mu;
    float rs = rsqrtf(var + 1e-5f);
    size_t ob = (size_t)b * COUT * 16384 + (size_t)y * 128 + x0 + px2;
#pragma unroll
    for (int j = 0; j < 16; ++j) {
      int oc = part * 16 + j;
      float v = outl[px2 * 65 + oc];
      out[ob + (size_t)oc * 16384] = (v - mu) * rs * lnw[oc] + lnb[oc];
    }
  }
}

extern "C" void kernel_launch(void* const* d_in, const int* in_sizes, int n_in,
                              void* d_out, int out_size, void* d_ws, size_t ws_size,
                              hipStream_t stream) {
  const float* evt      = (const float*)d_in[0];
  const float* efn      = (const float*)d_in[1];
  const float* ln_evt_w = (const float*)d_in[2];
  const float* ln_evt_b = (const float*)d_in[3];
  const float* ln_ef_w  = (const float*)d_in[4];
  const float* ln_ef_b  = (const float*)d_in[5];
  const float* ln_al_w  = (const float*)d_in[6];
  const float* ln_al_b  = (const float*)d_in[7];
  const float* off_w    = (const float*)d_in[8];
  const float* off_b    = (const float*)d_in[9];
  const float* mod_w    = (const float*)d_in[10];
  const float* mod_b    = (const float*)d_in[11];
  const float* reg_w    = (const float*)d_in[12];
  const float* reg_b    = (const float*)d_in[13];
  float* out = (float*)d_out;

  char* wsb = (char*)d_ws;
  __hip_bfloat16* oxb    = (__hip_bfloat16*)wsb;
  __hip_bfloat16* wct2   = (__hip_bfloat16*)(wsb + WCT_OFFB);
  __hip_bfloat16* wkt2   = (__hip_bfloat16*)(wsb + WKT_OFFB);

  ln_concat_prep<<<BATCH * HH * WW / 64, 256, 0, stream>>>(
      evt, efn, ln_evt_w, ln_evt_b, ln_ef_w, ln_ef_b,
      off_w, mod_w, reg_w, oxb, wct2, wkt2);
  conv_deform_fused<<<BATCH * HH * WW / 16, 64, 0, stream>>>(
      oxb, wct2, wkt2, off_b, mod_b, reg_b, ln_al_w, ln_al_b, out);
}

// Round 10
// 167.402 us; speedup vs baseline: 1.1272x; 1.1127x over previous
//
#include <hip/hip_runtime.h>
#include <hip/hip_bf16.h>

#define BATCH 4
#define HH 128
#define WW 128
#define CE 32
#define CF 64
#define CIN 96
#define COUT 64

typedef __bf16 bf16x8 __attribute__((ext_vector_type(8)));
typedef float f32x4 __attribute__((ext_vector_type(4)));
#define MFMA16(a, b, c) __builtin_amdgcn_mfma_f32_16x16x32_bf16(a, b, c, 0, 0, 0)
typedef union { uint4 u; bf16x8 v; } U8;

// ---- workspace byte offsets ----
#define OX_BYTES   (BATCH * HH * WW * CIN * 2)      // 12,582,912  bf16 NHWC
#define WCT_OFFB   OX_BYTES
#define WCT_BYTES  (27 * 32 * 32 * 2)               // 55,296 B
#define WKT_OFFB   (WCT_OFFB + WCT_BYTES)           // wkT2: 27*64*32 bf16 = 110,592 B

// Weight layouts (fragment-coalesced):
//   wcombT2[(tap*3+ks)*32 + oc][r]  r = lg*8+j -> channel c = ks*32 + r
//   wkT2  [(tap*3+ks)*64 + oc][r]

// Fused LN(evt)+LN(efnet)+concat -> ox bf16 NHWC, 64 px/block, 256 thr.
// Also repacks conv/deform weights to the fragment-coalesced layout.
__global__ __launch_bounds__(256) void ln_concat_prep(
    const float* __restrict__ evt, const float* __restrict__ efn,
    const float* __restrict__ w_e, const float* __restrict__ b_e,
    const float* __restrict__ w_f, const float* __restrict__ b_f,
    const float* __restrict__ off_w, const float* __restrict__ mod_w,
    const float* __restrict__ reg_w,
    __hip_bfloat16* __restrict__ ox,
    __hip_bfloat16* __restrict__ wcombT2,
    __hip_bfloat16* __restrict__ wkT2) {
  __shared__ float vals[64 * 97];
  __shared__ float part[4 * 64 * 4];
  __shared__ float stat[64 * 4];

  // ---- weight repack ----
  {
    int e = blockIdx.x * 256 + threadIdx.x;
    const int TOT1 = 27 * 32 * 32;   // 27648
    const int TOT2 = 27 * 64 * 32;   // 55296
    if (e < TOT1) {
      int r = e & 31, g = e >> 5;
      int oc = g & 31, tks = g >> 5;
      int tap = tks / 3, ks = tks % 3, c = ks * 32 + r;
      float v = 0.f;
      if (oc < 18)      v = off_w[(oc * CIN + c) * 9 + tap];
      else if (oc < 27) v = mod_w[((oc - 18) * CIN + c) * 9 + tap];
      wcombT2[e] = __float2bfloat16(v);
    } else if (e < TOT1 + TOT2) {
      int e2 = e - TOT1;
      int r = e2 & 31, g = e2 >> 5;
      int oc = g & 63, tks = g >> 6;
      int tap = tks / 3, ks = tks % 3, c = ks * 32 + r;
      wkT2[e2] = __float2bfloat16(reg_w[(oc * CIN + c) * 9 + tap]);
    }
  }

  int bid = blockIdx.x;
  int wg = (bid & 7) * 128 + (bid >> 3);     // XCD-chunked swizzle (1024 = 8*128)
  int p0 = wg * 64;
  int b = p0 >> 14, y = (p0 >> 7) & 127, x0 = p0 & 127;
  int t = threadIdx.x, px = t & 63, g = t >> 6;

  float sE = 0.f, sE2 = 0.f, sF = 0.f, sF2 = 0.f;
  const float* pe = evt + (((size_t)b * CE) << 14) + (y << 7) + x0 + px;
#pragma unroll
  for (int j = 0; j < 8; ++j) {
    int c = g * 8 + j;
    float v = pe[(size_t)c << 14];
    vals[px * 97 + c] = v; sE += v; sE2 += v * v;
  }
  const float* pf = efn + (((size_t)b * CF) << 14) + (y << 7) + x0 + px;
#pragma unroll
  for (int j = 0; j < 16; ++j) {
    int c = g * 16 + j;
    float v = pf[(size_t)c << 14];
    vals[px * 97 + CE + c] = v; sF += v; sF2 += v * v;
  }
  {
    float4 p4 = {sE, sE2, sF, sF2};
    *(float4*)&part[(g * 64 + px) * 4] = p4;
  }
  __syncthreads();
  if (g == 0) {
    float aE = 0.f, aE2 = 0.f, aF = 0.f, aF2 = 0.f;
#pragma unroll
    for (int gg = 0; gg < 4; ++gg) {
      float4 p4 = *(const float4*)&part[(gg * 64 + px) * 4];
      aE += p4.x; aE2 += p4.y; aF += p4.z; aF2 += p4.w;
    }
    float muE = aE * (1.f / CE);
    float vE = aE2 * (1.f / CE) - muE * muE;
    float muF = aF * (1.f / CF);
    float vF = aF2 * (1.f / CF) - muF * muF;
    float4 s4 = {muE, rsqrtf(vE + 1e-5f), muF, rsqrtf(vF + 1e-5f)};
    *(float4*)&stat[px * 4] = s4;
  }
  __syncthreads();
  uint* orow = (uint*)(ox + (size_t)p0 * CIN);
#pragma unroll
  for (int i = 0; i < 12; ++i) {
    int e = i * 256 + t;
    int xx = e / 48, c = (e % 48) * 2;
    float v0 = vals[xx * 97 + c], v1 = vals[xx * 97 + c + 1];
    float mu, rs, lw0, lb0, lw1, lb1;
    if (c < CE) {
      mu = stat[xx * 4 + 0]; rs = stat[xx * 4 + 1];
      lw0 = w_e[c]; lb0 = b_e[c]; lw1 = w_e[c + 1]; lb1 = b_e[c + 1];
    } else {
      mu = stat[xx * 4 + 2]; rs = stat[xx * 4 + 3];
      lw0 = w_f[c - CE]; lb0 = b_f[c - CE]; lw1 = w_f[c + 1 - CE]; lb1 = b_f[c + 1 - CE];
    }
    float o0 = (v0 - mu) * rs * lw0 + lb0;
    float o1 = (v1 - mu) * rs * lw1 + lb1;
    __hip_bfloat16 h0 = __float2bfloat16(o0), h1 = __float2bfloat16(o1);
    orow[e] = ((uint)*(unsigned short*)&h1 << 16) | (uint)*(unsigned short*)&h0;
  }
}

__device__ __forceinline__ uint blend1(uint u0, uint u1, uint u2, uint u3,
                                       float w0, float w1, float w2, float w3) {
  float lo = w0 * __uint_as_float(u0 << 16) + w1 * __uint_as_float(u1 << 16)
           + w2 * __uint_as_float(u2 << 16) + w3 * __uint_as_float(u3 << 16);
  float hi = w0 * __uint_as_float(u0 & 0xffff0000u) + w1 * __uint_as_float(u1 & 0xffff0000u)
           + w2 * __uint_as_float(u2 & 0xffff0000u) + w3 * __uint_as_float(u3 & 0xffff0000u);
  __hip_bfloat16 bl = __float2bfloat16(lo), bh = __float2bfloat16(hi);
  return ((uint)*(unsigned short*)&bh << 16) | (uint)*(unsigned short*)&bl;
}

// Fused conv(27ch)->deform->bias/leaky/LN with LDS-staged input window.
// 64-px row tile, 256 thr (4 waves, each owns a 16-px M-tile).
// Window: rows y-2..y+2, cols x0-2..x0+66 (5x69x96 bf16 = 66.2 KB), staged
// coalesced + zero-padded once -> 1 barrier. Conv A and all bilinear corner
// reads are ds_read_b128 (no TA); rare out-of-window corners (|off|>~1)
// fall back to global loads. 2 barriers total.
__global__ __launch_bounds__(256) void conv_deform_fused(
    const __hip_bfloat16* __restrict__ ox,
    const __hip_bfloat16* __restrict__ wct2,
    const __hip_bfloat16* __restrict__ wkt2,
    const float* __restrict__ off_b, const float* __restrict__ mod_b,
    const float* __restrict__ reg_b,
    const float* __restrict__ lnw, const float* __restrict__ lnb,
    float* __restrict__ out) {
  __shared__ short win[5 * 69 * CIN];   // 66,240 B window
  __shared__ float offm[64 * 28];       // 7,168 B
  float* outl = (float*)win;            // epilogue alias (after barrier)

  int bid = blockIdx.x;
  int wg = (bid & 7) * 128 + (bid >> 3);   // XCD-chunked swizzle
  int p0 = wg * 64;
  int b = p0 >> 14, y = (p0 >> 7) & 127, x0 = p0 & 127;
  const __hip_bfloat16* oxb = ox + (((size_t)b) << 14) * CIN;

  int t = threadIdx.x, lane = t & 63, wv = t >> 6;
  int lr = lane & 15, lg = lane >> 4;
  int pxw = (wv << 4) + lr;                // this lane's A-row pixel

  // ---- stage window (coalesced rows, zero-padded outside image) ----
  for (int u = t; u < 5 * 69 * 12; u += 256) {
    int c8 = u % 12, pos = u / 12;
    int wr = pos / 69, wc = pos % 69;
    int gy = y - 2 + wr, gx = x0 - 2 + wc;
    uint4 v = {0u, 0u, 0u, 0u};
    if ((unsigned)gy < 128u && (unsigned)gx < 128u)
      v = *(const uint4*)(oxb + (size_t)((gy << 7) + gx) * CIN + c8 * 8);
    *(uint4*)&win[pos * CIN + c8 * 8] = v;
  }
  __syncthreads();

  // ---- conv phase: A from window (zero-pad already correct) ----
  f32x4 cc0 = {0.f,0.f,0.f,0.f}, cc1 = {0.f,0.f,0.f,0.f};
#pragma unroll
  for (int tap = 0; tap < 9; ++tap) {
    int wr = tap / 3 + 1;                  // dy + 2
    int wc = pxw + tap % 3 + 1;            // px + dx + 2
    const short* ar = &win[(wr * 69 + wc) * CIN + lg * 8];
#pragma unroll
    for (int ks = 0; ks < 3; ++ks) {
      bf16x8 a = *(const bf16x8*)(ar + ks * 32);
      const __hip_bfloat16* wb = wct2 + (size_t)((tap * 3 + ks) * 32) * 32 + lg * 8;
      U8 w0, w1;
      w0.u = *(const uint4*)(wb + lr * 32);
      w1.u = *(const uint4*)(wb + (16 + lr) * 32);
      cc0 = MFMA16(a, w0.v, cc0);
      cc1 = MFMA16(a, w1.v, cc1);
    }
  }
  // offm epilogue — wave-local (LDS ops in wave program order)
#pragma unroll
  for (int nt = 0; nt < 2; ++nt) {
    int oc = nt * 16 + lr;
    if (oc < 27) {
      float bia = (oc < 18) ? off_b[oc] : mod_b[oc - 18];
      f32x4 a = nt ? cc1 : cc0;
#pragma unroll
      for (int r = 0; r < 4; ++r) {
        float v = a[r] + bia;
        if (oc >= 18) v = 2.f / (1.f + __expf(-v));
        offm[((wv << 4) + (lg << 2) + r) * 28 + oc] = v;
      }
    }
  }

  // ---- deform phase: corners from window (ds_read), rare global fallback ----
  const float* om = offm + pxw * 28;
  f32x4 ac0 = {0.f,0.f,0.f,0.f}, ac1 = {0.f,0.f,0.f,0.f};
  f32x4 ac2 = {0.f,0.f,0.f,0.f}, ac3 = {0.f,0.f,0.f,0.f};

#pragma unroll
  for (int tap = 0; tap < 9; ++tap) {
    float dyv = om[2 * tap], dxv = om[2 * tap + 1], mk = om[18 + tap];
    float psy = (float)(y + tap / 3 - 1) + dyv;
    float psx = (float)(x0 + pxw + tap % 3 - 1) + dxv;
    float fy = floorf(psy), fx = floorf(psx);
    float wy1 = psy - fy, wx1 = psx - fx;
    float wy0 = 1.f - wy1, wx0 = 1.f - wx1;
    int iy0 = (int)fy, ix0 = (int)fx, iy1 = iy0 + 1, ix1 = ix0 + 1;
    float vy0 = ((unsigned)iy0 < 128u) ? 1.f : 0.f;
    float vy1 = ((unsigned)iy1 < 128u) ? 1.f : 0.f;
    float vx0 = ((unsigned)ix0 < 128u) ? 1.f : 0.f;
    float vx1 = ((unsigned)ix1 < 128u) ? 1.f : 0.f;
    int cy0 = min(max(iy0, 0), 127), cy1 = min(max(iy1, 0), 127);
    int cx0 = min(max(ix0, 0), 127), cx1 = min(max(ix1, 0), 127);
    float pw0 = wy0 * wx0 * vy0 * vx0 * mk;
    float pw1 = wy0 * wx1 * vy0 * vx1 * mk;
    float pw2 = wy1 * wx0 * vy1 * vx0 * mk;
    float pw3 = wy1 * wx1 * vy1 * vx1 * mk;
    // window coords
    int ra = cy0 - y + 2, rb = cy1 - y + 2;
    int ca = cx0 - x0 + 2, cb = cx1 - x0 + 2;
    bool ina = (unsigned)ra < 5u, inb = (unsigned)rb < 5u;
    bool inca = (unsigned)ca < 69u, incb = (unsigned)cb < 69u;
    int w0o = (ina && inca) ? (ra * 69 + ca) * CIN : -1;
    int w1o = (ina && incb) ? (ra * 69 + cb) * CIN : -1;
    int w2o = (inb && inca) ? (rb * 69 + ca) * CIN : -1;
    int w3o = (inb && incb) ? (rb * 69 + cb) * CIN : -1;
    int g0 = ((cy0 << 7) + cx0) * CIN, g1 = ((cy0 << 7) + cx1) * CIN;
    int g2 = ((cy1 << 7) + cx0) * CIN, g3 = ((cy1 << 7) + cx1) * CIN;

#pragma unroll
    for (int ks = 0; ks < 3; ++ks) {
      int koff = ks * 32 + lg * 8;
      U8 q0, q1, q2, q3;
      q0.v = *(const bf16x8*)&win[(w0o < 0 ? 0 : w0o) + koff];
      q1.v = *(const bf16x8*)&win[(w1o < 0 ? 0 : w1o) + koff];
      q2.v = *(const bf16x8*)&win[(w2o < 0 ? 0 : w2o) + koff];
      q3.v = *(const bf16x8*)&win[(w3o < 0 ? 0 : w3o) + koff];
      if (w0o < 0) q0.u = *(const uint4*)(oxb + g0 + koff);
      if (w1o < 0) q1.u = *(const uint4*)(oxb + g1 + koff);
      if (w2o < 0) q2.u = *(const uint4*)(oxb + g2 + koff);
      if (w3o < 0) q3.u = *(const uint4*)(oxb + g3 + koff);
      U8 fa;
      fa.u.x = blend1(q0.u.x, q1.u.x, q2.u.x, q3.u.x, pw0, pw1, pw2, pw3);
      fa.u.y = blend1(q0.u.y, q1.u.y, q2.u.y, q3.u.y, pw0, pw1, pw2, pw3);
      fa.u.z = blend1(q0.u.z, q1.u.z, q2.u.z, q3.u.z, pw0, pw1, pw2, pw3);
      fa.u.w = blend1(q0.u.w, q1.u.w, q2.u.w, q3.u.w, pw0, pw1, pw2, pw3);
      const __hip_bfloat16* wb = wkt2 + (size_t)((tap * 3 + ks) * 64) * 32 + lg * 8;
      U8 b0, b1, b2, b3;
      b0.u = *(const uint4*)(wb + lr * 32);
      b1.u = *(const uint4*)(wb + (16 + lr) * 32);
      b2.u = *(const uint4*)(wb + (32 + lr) * 32);
      b3.u = *(const uint4*)(wb + (48 + lr) * 32);
      ac0 = MFMA16(fa.v, b0.v, ac0);
      ac1 = MFMA16(fa.v, b1.v, ac1);
      ac2 = MFMA16(fa.v, b2.v, ac2);
      ac3 = MFMA16(fa.v, b3.v, ac3);
    }
  }
  __syncthreads();   // window reads done; outl may alias win

  // ---- epilogue: bias+leaky -> outl (wave-local), channel-LN, store ----
#pragma unroll
  for (int nt = 0; nt < 4; ++nt) {
    int oc = nt * 16 + lr;
    float bia = reg_b[oc];
    f32x4 a = (nt == 0) ? ac0 : (nt == 1) ? ac1 : (nt == 2) ? ac2 : ac3;
#pragma unroll
    for (int r = 0; r < 4; ++r) {
      float v = a[r] + bia;
      v = (v >= 0.f) ? v : 0.2f * v;
      outl[((wv << 4) + (lg << 2) + r) * 65 + oc] = v;
    }
  }
  {
    int px2 = (wv << 4) + (lane >> 2), part = lane & 3;
    float s = 0.f, s2 = 0.f;
#pragma unroll
    for (int j = 0; j < 16; ++j) {
      float v = outl[px2 * 65 + part * 16 + j];
      s += v; s2 += v * v;
    }
    s += __shfl_xor(s, 1); s2 += __shfl_xor(s2, 1);
    s += __shfl_xor(s, 2); s2 += __shfl_xor(s2, 2);
    float mu = s * (1.f / 64.f);
    float var = s2 * (1.f / 64.f) - mu * mu;
    float rs = rsqrtf(var + 1e-5f);
    size_t ob = (size_t)b * COUT * 16384 + (size_t)y * 128 + x0 + px2;
#pragma unroll
    for (int j = 0; j < 16; ++j) {
      int oc = part * 16 + j;
      float v = outl[px2 * 65 + oc];
      out[ob + (size_t)oc * 16384] = (v - mu) * rs * lnw[oc] + lnb[oc];
    }
  }
}

extern "C" void kernel_launch(void* const* d_in, const int* in_sizes, int n_in,
                              void* d_out, int out_size, void* d_ws, size_t ws_size,
                              hipStream_t stream) {
  const float* evt      = (const float*)d_in[0];
  const float* efn      = (const float*)d_in[1];
  const float* ln_evt_w = (const float*)d_in[2];
  const float* ln_evt_b = (const float*)d_in[3];
  const float* ln_ef_w  = (const float*)d_in[4];
  const float* ln_ef_b  = (const float*)d_in[5];
  const float* ln_al_w  = (const float*)d_in[6];
  const float* ln_al_b  = (const float*)d_in[7];
  const float* off_w    = (const float*)d_in[8];
  const float* off_b    = (const float*)d_in[9];
  const float* mod_w    = (const float*)d_in[10];
  const float* mod_b    = (const float*)d_in[11];
  const float* reg_w    = (const float*)d_in[12];
  const float* reg_b    = (const float*)d_in[13];
  float* out = (float*)d_out;

  char* wsb = (char*)d_ws;
  __hip_bfloat16* oxb    = (__hip_bfloat16*)wsb;
  __hip_bfloat16* wct2   = (__hip_bfloat16*)(wsb + WCT_OFFB);
  __hip_bfloat16* wkt2   = (__hip_bfloat16*)(wsb + WKT_OFFB);

  ln_concat_prep<<<BATCH * HH * WW / 64, 256, 0, stream>>>(
      evt, efn, ln_evt_w, ln_evt_b, ln_ef_w, ln_ef_b,
      off_w, mod_w, reg_w, oxb, wct2, wkt2);
  conv_deform_fused<<<BATCH * HH * WW / 64, 256, 0, stream>>>(
      oxb, wct2, wkt2, off_b, mod_b, reg_b, ln_al_w, ln_al_b, out);
}

// Round 11
// 162.786 us; speedup vs baseline: 1.1591x; 1.0284x over previous
//
#include <hip/hip_runtime.h>
#include <hip/hip_bf16.h>

#define BATCH 4
#define HH 128
#define WW 128
#define CE 32
#define CF 64
#define CIN 96
#define COUT 64

// fused-kernel tile: 2 rows x 32 cols = 64 px
#define WROWS 6
#define WCOLS 36
#define WSTR 104      // padded row stride (bf16): 52 dwords -> 2-way max (free)
#define OFFSTR 29     // offm stride (f32): gcd(29,32)=1 -> conflict-free

typedef __bf16 bf16x8 __attribute__((ext_vector_type(8)));
typedef float f32x4 __attribute__((ext_vector_type(4)));
#define MFMA16(a, b, c) __builtin_amdgcn_mfma_f32_16x16x32_bf16(a, b, c, 0, 0, 0)
typedef union { uint4 u; bf16x8 v; } U8;

// ---- workspace byte offsets ----
#define OX_BYTES   (BATCH * HH * WW * CIN * 2)      // 12,582,912  bf16 NHWC
#define WCT_OFFB   OX_BYTES
#define WCT_BYTES  (27 * 32 * 32 * 2)               // 55,296 B
#define WKT_OFFB   (WCT_OFFB + WCT_BYTES)           // wkT2: 27*64*32 bf16 = 110,592 B

// Weight layouts (fragment-coalesced):
//   wcombT2[(tap*3+ks)*32 + oc][r]  r = lg*8+j -> channel c = ks*32 + r
//   wkT2  [(tap*3+ks)*64 + oc][r]

// Fused LN(evt)+LN(efnet)+concat -> ox bf16 NHWC, 64 px/block, 256 thr.
// Also repacks conv/deform weights to the fragment-coalesced layout.
__global__ __launch_bounds__(256) void ln_concat_prep(
    const float* __restrict__ evt, const float* __restrict__ efn,
    const float* __restrict__ w_e, const float* __restrict__ b_e,
    const float* __restrict__ w_f, const float* __restrict__ b_f,
    const float* __restrict__ off_w, const float* __restrict__ mod_w,
    const float* __restrict__ reg_w,
    __hip_bfloat16* __restrict__ ox,
    __hip_bfloat16* __restrict__ wcombT2,
    __hip_bfloat16* __restrict__ wkT2) {
  __shared__ float vals[64 * 97];
  __shared__ float part[4 * 64 * 4];
  __shared__ float stat[64 * 4];

  // ---- weight repack ----
  {
    int e = blockIdx.x * 256 + threadIdx.x;
    const int TOT1 = 27 * 32 * 32;   // 27648
    const int TOT2 = 27 * 64 * 32;   // 55296
    if (e < TOT1) {
      int r = e & 31, g = e >> 5;
      int oc = g & 31, tks = g >> 5;
      int tap = tks / 3, ks = tks % 3, c = ks * 32 + r;
      float v = 0.f;
      if (oc < 18)      v = off_w[(oc * CIN + c) * 9 + tap];
      else if (oc < 27) v = mod_w[((oc - 18) * CIN + c) * 9 + tap];
      wcombT2[e] = __float2bfloat16(v);
    } else if (e < TOT1 + TOT2) {
      int e2 = e - TOT1;
      int r = e2 & 31, g = e2 >> 5;
      int oc = g & 63, tks = g >> 6;
      int tap = tks / 3, ks = tks % 3, c = ks * 32 + r;
      wkT2[e2] = __float2bfloat16(reg_w[(oc * CIN + c) * 9 + tap]);
    }
  }

  int bid = blockIdx.x;
  int wg = (bid & 7) * 128 + (bid >> 3);     // XCD-chunked swizzle (1024 = 8*128)
  int p0 = wg * 64;
  int b = p0 >> 14, y = (p0 >> 7) & 127, x0 = p0 & 127;
  int t = threadIdx.x, px = t & 63, g = t >> 6;

  float sE = 0.f, sE2 = 0.f, sF = 0.f, sF2 = 0.f;
  const float* pe = evt + (((size_t)b * CE) << 14) + (y << 7) + x0 + px;
#pragma unroll
  for (int j = 0; j < 8; ++j) {
    int c = g * 8 + j;
    float v = pe[(size_t)c << 14];
    vals[px * 97 + c] = v; sE += v; sE2 += v * v;
  }
  const float* pf = efn + (((size_t)b * CF) << 14) + (y << 7) + x0 + px;
#pragma unroll
  for (int j = 0; j < 16; ++j) {
    int c = g * 16 + j;
    float v = pf[(size_t)c << 14];
    vals[px * 97 + CE + c] = v; sF += v; sF2 += v * v;
  }
  {
    float4 p4 = {sE, sE2, sF, sF2};
    *(float4*)&part[(g * 64 + px) * 4] = p4;
  }
  __syncthreads();
  if (g == 0) {
    float aE = 0.f, aE2 = 0.f, aF = 0.f, aF2 = 0.f;
#pragma unroll
    for (int gg = 0; gg < 4; ++gg) {
      float4 p4 = *(const float4*)&part[(gg * 64 + px) * 4];
      aE += p4.x; aE2 += p4.y; aF += p4.z; aF2 += p4.w;
    }
    float muE = aE * (1.f / CE);
    float vE = aE2 * (1.f / CE) - muE * muE;
    float muF = aF * (1.f / CF);
    float vF = aF2 * (1.f / CF) - muF * muF;
    float4 s4 = {muE, rsqrtf(vE + 1e-5f), muF, rsqrtf(vF + 1e-5f)};
    *(float4*)&stat[px * 4] = s4;
  }
  __syncthreads();
  uint* orow = (uint*)(ox + (size_t)p0 * CIN);
#pragma unroll
  for (int i = 0; i < 12; ++i) {
    int e = i * 256 + t;
    int xx = e / 48, c = (e % 48) * 2;
    float v0 = vals[xx * 97 + c], v1 = vals[xx * 97 + c + 1];
    float mu, rs, lw0, lb0, lw1, lb1;
    if (c < CE) {
      mu = stat[xx * 4 + 0]; rs = stat[xx * 4 + 1];
      lw0 = w_e[c]; lb0 = b_e[c]; lw1 = w_e[c + 1]; lb1 = b_e[c + 1];
    } else {
      mu = stat[xx * 4 + 2]; rs = stat[xx * 4 + 3];
      lw0 = w_f[c - CE]; lb0 = b_f[c - CE]; lw1 = w_f[c + 1 - CE]; lb1 = b_f[c + 1 - CE];
    }
    float o0 = (v0 - mu) * rs * lw0 + lb0;
    float o1 = (v1 - mu) * rs * lw1 + lb1;
    __hip_bfloat16 h0 = __float2bfloat16(o0), h1 = __float2bfloat16(o1);
    orow[e] = ((uint)*(unsigned short*)&h1 << 16) | (uint)*(unsigned short*)&h0;
  }
}

__device__ __forceinline__ uint blend1(uint u0, uint u1, uint u2, uint u3,
                                       float w0, float w1, float w2, float w3) {
  float lo = w0 * __uint_as_float(u0 << 16) + w1 * __uint_as_float(u1 << 16)
           + w2 * __uint_as_float(u2 << 16) + w3 * __uint_as_float(u3 << 16);
  float hi = w0 * __uint_as_float(u0 & 0xffff0000u) + w1 * __uint_as_float(u1 & 0xffff0000u)
           + w2 * __uint_as_float(u2 & 0xffff0000u) + w3 * __uint_as_float(u3 & 0xffff0000u);
  __hip_bfloat16 bl = __float2bfloat16(lo), bh = __float2bfloat16(hi);
  return ((uint)*(unsigned short*)&bh << 16) | (uint)*(unsigned short*)&bl;
}

// Fused conv(27ch)->deform->bias/leaky/LN, LDS window, 2x32-px tile.
// Window rows y0-2..y0+3, cols x0-2..x0+33 (6x36), row stride padded to 104
// bf16 (2-way max bank aliasing = free). 3 blocks/CU (52.3 KB LDS).
__global__ __launch_bounds__(256) void conv_deform_fused(
    const __hip_bfloat16* __restrict__ ox,
    const __hip_bfloat16* __restrict__ wct2,
    const __hip_bfloat16* __restrict__ wkt2,
    const float* __restrict__ off_b, const float* __restrict__ mod_b,
    const float* __restrict__ reg_b,
    const float* __restrict__ lnw, const float* __restrict__ lnb,
    float* __restrict__ out) {
  __shared__ short win[WROWS * WCOLS * WSTR];   // 44,928 B
  __shared__ float offm[64 * OFFSTR];           // 7,424 B
  float* outl = (float*)win;                    // epilogue alias (after barrier)

  int bid = blockIdx.x;
  int wg = (bid & 7) * 128 + (bid >> 3);   // XCD-chunked swizzle (1024 = 8*128)
  int b = wg >> 8;                          // 256 tiles per batch
  int rem = wg & 255;
  int y0 = (rem >> 2) * 2;                  // 64 y-tiles of 2 rows
  int x0 = (rem & 3) * 32;                  // 4 x-tiles of 32 cols
  const __hip_bfloat16* oxb = ox + (((size_t)b) << 14) * CIN;

  int t = threadIdx.x, lane = t & 63, wv = t >> 6;
  int lr = lane & 15, lg = lane >> 4;
  int pxrow = wv >> 1;                      // this lane's A-row pixel (row, col)
  int pxcol = ((wv & 1) << 4) + lr;

  // ---- stage window (coalesced rows, zero-padded outside image) ----
  for (int u = t; u < WROWS * WCOLS * 12; u += 256) {
    int c8 = u % 12, pos = u / 12;
    int wr = pos / WCOLS, wc = pos % WCOLS;
    int gy = y0 - 2 + wr, gx = x0 - 2 + wc;
    uint4 v = {0u, 0u, 0u, 0u};
    if ((unsigned)gy < 128u && (unsigned)gx < 128u)
      v = *(const uint4*)(oxb + (size_t)((gy << 7) + gx) * CIN + c8 * 8);
    *(uint4*)&win[pos * WSTR + c8 * 8] = v;
  }
  __syncthreads();

  // ---- conv phase: A from window (zero-pad already correct) ----
  f32x4 cc0 = {0.f,0.f,0.f,0.f}, cc1 = {0.f,0.f,0.f,0.f};
#pragma unroll
  for (int tap = 0; tap < 9; ++tap) {
    int wr = pxrow + tap / 3 + 1;           // + dy + 2
    int wc = pxcol + tap % 3 + 1;           // + dx + 2
    const short* ar = &win[(wr * WCOLS + wc) * WSTR + lg * 8];
#pragma unroll
    for (int ks = 0; ks < 3; ++ks) {
      bf16x8 a = *(const bf16x8*)(ar + ks * 32);
      const __hip_bfloat16* wb = wct2 + (size_t)((tap * 3 + ks) * 32) * 32 + lg * 8;
      U8 w0, w1;
      w0.u = *(const uint4*)(wb + lr * 32);
      w1.u = *(const uint4*)(wb + (16 + lr) * 32);
      cc0 = MFMA16(a, w0.v, cc0);
      cc1 = MFMA16(a, w1.v, cc1);
    }
  }
  // offm epilogue — wave-local (LDS ops in wave program order)
#pragma unroll
  for (int nt = 0; nt < 2; ++nt) {
    int oc = nt * 16 + lr;
    if (oc < 27) {
      float bia = (oc < 18) ? off_b[oc] : mod_b[oc - 18];
      f32x4 a = nt ? cc1 : cc0;
#pragma unroll
      for (int r = 0; r < 4; ++r) {
        float v = a[r] + bia;
        if (oc >= 18) v = 2.f / (1.f + __expf(-v));
        offm[((wv << 4) + (lg << 2) + r) * OFFSTR + oc] = v;
      }
    }
  }

  // ---- deform phase: corners from window (ds_read), rare global fallback ----
  const float* om = offm + ((wv << 4) + lr) * OFFSTR;
  f32x4 ac0 = {0.f,0.f,0.f,0.f}, ac1 = {0.f,0.f,0.f,0.f};
  f32x4 ac2 = {0.f,0.f,0.f,0.f}, ac3 = {0.f,0.f,0.f,0.f};

#pragma unroll
  for (int tap = 0; tap < 9; ++tap) {
    float dyv = om[2 * tap], dxv = om[2 * tap + 1], mk = om[18 + tap];
    float psy = (float)(y0 + pxrow + tap / 3 - 1) + dyv;
    float psx = (float)(x0 + pxcol + tap % 3 - 1) + dxv;
    float fy = floorf(psy), fx = floorf(psx);
    float wy1 = psy - fy, wx1 = psx - fx;
    float wy0 = 1.f - wy1, wx0 = 1.f - wx1;
    int iy0 = (int)fy, ix0 = (int)fx, iy1 = iy0 + 1, ix1 = ix0 + 1;
    float vy0 = ((unsigned)iy0 < 128u) ? 1.f : 0.f;
    float vy1 = ((unsigned)iy1 < 128u) ? 1.f : 0.f;
    float vx0 = ((unsigned)ix0 < 128u) ? 1.f : 0.f;
    float vx1 = ((unsigned)ix1 < 128u) ? 1.f : 0.f;
    int cy0 = min(max(iy0, 0), 127), cy1 = min(max(iy1, 0), 127);
    int cx0 = min(max(ix0, 0), 127), cx1 = min(max(ix1, 0), 127);
    float pw0 = wy0 * wx0 * vy0 * vx0 * mk;
    float pw1 = wy0 * wx1 * vy0 * vx1 * mk;
    float pw2 = wy1 * wx0 * vy1 * vx0 * mk;
    float pw3 = wy1 * wx1 * vy1 * vx1 * mk;
    // window coords
    int ra = cy0 - y0 + 2, rb = cy1 - y0 + 2;
    int ca = cx0 - x0 + 2, cb = cx1 - x0 + 2;
    bool ina = (unsigned)ra < (unsigned)WROWS, inb = (unsigned)rb < (unsigned)WROWS;
    bool inca = (unsigned)ca < (unsigned)WCOLS, incb = (unsigned)cb < (unsigned)WCOLS;
    int w0o = (ina && inca) ? (ra * WCOLS + ca) * WSTR : -1;
    int w1o = (ina && incb) ? (ra * WCOLS + cb) * WSTR : -1;
    int w2o = (inb && inca) ? (rb * WCOLS + ca) * WSTR : -1;
    int w3o = (inb && incb) ? (rb * WCOLS + cb) * WSTR : -1;
    int g0 = ((cy0 << 7) + cx0) * CIN, g1 = ((cy0 << 7) + cx1) * CIN;
    int g2 = ((cy1 << 7) + cx0) * CIN, g3 = ((cy1 << 7) + cx1) * CIN;

#pragma unroll
    for (int ks = 0; ks < 3; ++ks) {
      int koff = ks * 32 + lg * 8;
      U8 q0, q1, q2, q3;
      q0.v = *(const bf16x8*)&win[(w0o < 0 ? 0 : w0o) + koff];
      q1.v = *(const bf16x8*)&win[(w1o < 0 ? 0 : w1o) + koff];
      q2.v = *(const bf16x8*)&win[(w2o < 0 ? 0 : w2o) + koff];
      q3.v = *(const bf16x8*)&win[(w3o < 0 ? 0 : w3o) + koff];
      if (w0o < 0) q0.u = *(const uint4*)(oxb + g0 + koff);
      if (w1o < 0) q1.u = *(const uint4*)(oxb + g1 + koff);
      if (w2o < 0) q2.u = *(const uint4*)(oxb + g2 + koff);
      if (w3o < 0) q3.u = *(const uint4*)(oxb + g3 + koff);
      U8 fa;
      fa.u.x = blend1(q0.u.x, q1.u.x, q2.u.x, q3.u.x, pw0, pw1, pw2, pw3);
      fa.u.y = blend1(q0.u.y, q1.u.y, q2.u.y, q3.u.y, pw0, pw1, pw2, pw3);
      fa.u.z = blend1(q0.u.z, q1.u.z, q2.u.z, q3.u.z, pw0, pw1, pw2, pw3);
      fa.u.w = blend1(q0.u.w, q1.u.w, q2.u.w, q3.u.w, pw0, pw1, pw2, pw3);
      const __hip_bfloat16* wb = wkt2 + (size_t)((tap * 3 + ks) * 64) * 32 + lg * 8;
      U8 b0, b1, b2, b3;
      b0.u = *(const uint4*)(wb + lr * 32);
      b1.u = *(const uint4*)(wb + (16 + lr) * 32);
      b2.u = *(const uint4*)(wb + (32 + lr) * 32);
      b3.u = *(const uint4*)(wb + (48 + lr) * 32);
      ac0 = MFMA16(fa.v, b0.v, ac0);
      ac1 = MFMA16(fa.v, b1.v, ac1);
      ac2 = MFMA16(fa.v, b2.v, ac2);
      ac3 = MFMA16(fa.v, b3.v, ac3);
    }
  }
  __syncthreads();   // window reads done; outl may alias win

  // ---- epilogue: bias+leaky -> outl (wave-local), channel-LN, store ----
#pragma unroll
  for (int nt = 0; nt < 4; ++nt) {
    int oc = nt * 16 + lr;
    float bia = reg_b[oc];
    f32x4 a = (nt == 0) ? ac0 : (nt == 1) ? ac1 : (nt == 2) ? ac2 : ac3;
#pragma unroll
    for (int r = 0; r < 4; ++r) {
      float v = a[r] + bia;
      v = (v >= 0.f) ? v : 0.2f * v;
      outl[((wv << 4) + (lg << 2) + r) * 65 + oc] = v;
    }
  }
  {
    int px2 = (wv << 4) + (lane >> 2), part = lane & 3;
    int orow = px2 >> 5, ocol = px2 & 31;
    float s = 0.f, s2 = 0.f;
#pragma unroll
    for (int j = 0; j < 16; ++j) {
      float v = outl[px2 * 65 + part * 16 + j];
      s += v; s2 += v * v;
    }
    s += __shfl_xor(s, 1); s2 += __shfl_xor(s2, 1);
    s += __shfl_xor(s, 2); s2 += __shfl_xor(s2, 2);
    float mu = s * (1.f / 64.f);
    float var = s2 * (1.f / 64.f) - mu * mu;
    float rs = rsqrtf(var + 1e-5f);
    size_t ob = (size_t)b * COUT * 16384 + (size_t)(y0 + orow) * 128 + x0 + ocol;
#pragma unroll
    for (int j = 0; j < 16; ++j) {
      int oc = part * 16 + j;
      float v = outl[px2 * 65 + oc];
      out[ob + (size_t)oc * 16384] = (v - mu) * rs * lnw[oc] + lnb[oc];
    }
  }
}

extern "C" void kernel_launch(void* const* d_in, const int* in_sizes, int n_in,
                              void* d_out, int out_size, void* d_ws, size_t ws_size,
                              hipStream_t stream) {
  const float* evt      = (const float*)d_in[0];
  const float* efn      = (const float*)d_in[1];
  const float* ln_evt_w = (const float*)d_in[2];
  const float* ln_evt_b = (const float*)d_in[3];
  const float* ln_ef_w  = (const float*)d_in[4];
  const float* ln_ef_b  = (const float*)d_in[5];
  const float* ln_al_w  = (const float*)d_in[6];
  const float* ln_al_b  = (const float*)d_in[7];
  const float* off_w    = (const float*)d_in[8];
  const float* off_b    = (const float*)d_in[9];
  const float* mod_w    = (const float*)d_in[10];
  const float* mod_b    = (const float*)d_in[11];
  const float* reg_w    = (const float*)d_in[12];
  const float* reg_b    = (const float*)d_in[13];
  float* out = (float*)d_out;

  char* wsb = (char*)d_ws;
  __hip_bfloat16* oxb    = (__hip_bfloat16*)wsb;
  __hip_bfloat16* wct2   = (__hip_bfloat16*)(wsb + WCT_OFFB);
  __hip_bfloat16* wkt2   = (__hip_bfloat16*)(wsb + WKT_OFFB);

  ln_concat_prep<<<BATCH * HH * WW / 64, 256, 0, stream>>>(
      evt, efn, ln_evt_w, ln_evt_b, ln_ef_w, ln_ef_b,
      off_w, mod_w, reg_w, oxb, wct2, wkt2);
  conv_deform_fused<<<BATCH * HH * WW / 64, 256, 0, stream>>>(
      oxb, wct2, wkt2, off_b, mod_b, reg_b, ln_al_w, ln_al_b, out);
}